// Round 14
// baseline (166.015 us; speedup 1.0000x reference)
//
#include <hip/hip_runtime.h>
#include <hip/hip_bf16.h>

namespace {

constexpr int B = 16;
constexpr int N = 1024;
constexpr int K = 20;
constexpr int HID = 128;
constexpr float BOX = 10.0f;

constexpr int PPB = 4;                  // particles per block
constexpr int MROWS = PPB * K;          // 80 = 5 m-tiles exactly
constexpr int MT = 5;
constexpr int KP1 = 96;                 // layer-1 K padded 78 -> 96
constexpr int FP = 104;                 // fS row pitch (bf16); 208B rows
constexpr int H1P = 136;                // h1 row pitch (bf16); 272B rows
constexpr int SURVCAP = 128;
constexpr int NTHR = 8;

// radius ladder: r = 1.25 + 0.5i (i<7), last = catch-all (max possible r2 = 75)
constexpr float THRC[NTHR] = {1.5625f, 3.0625f, 5.0625f, 7.5625f,
                              10.5625f, 14.0625f, 18.0625f, 76.0f};

constexpr int GRID_SEL  = B * N / PPB;              // 4096
constexpr int CONV_ELEMS = 128 * KP1 + 128 * 128;   // 28672
constexpr int GRID_CONV = (CONV_ELEMS + 255) / 256; // 112

typedef __attribute__((ext_vector_type(8))) short short8;
typedef __attribute__((ext_vector_type(4))) float f32x4;

__device__ __forceinline__ float tanh_f(float x) {
    float e = __expf(2.0f * x);
    return 1.0f - 2.0f / (e + 1.0f);
}

__device__ __forceinline__ ushort bfb(float x) {
    __hip_bfloat16 h = __float2bfloat16(x);
    return __builtin_bit_cast(ushort, h);
}

// Exact min-image for |d| < 10: rint(fl(d/10)) == (d>5) - (d<-5).  (Sterbenz)
__device__ __forceinline__ float pbc(float d) {
    const float hi = __fsub_rn(d, BOX);
    const float lo = __fadd_rn(d, BOX);
    return d > 5.0f ? hi : (d < -5.0f ? lo : d);
}

// ---- kernel 1: weight preconversion (transposed, K-padded, hi/lo bf16 split ==
// f32 weights through 2 MFMAs). Must be a separate launch: fused kernel blocks
// read weights with no cross-block ordering guarantee.
__global__ __launch_bounds__(256) void conv_w_kernel(
    const float* __restrict__ w1, const float* __restrict__ w2,
    ushort* __restrict__ w1Th, ushort* __restrict__ w1Tl,
    ushort* __restrict__ w2Th, ushort* __restrict__ w2Tl)
{
    const int idx = blockIdx.x * 256 + threadIdx.x;
    if (idx < 128 * KP1) {
        const int n = idx / KP1, k = idx - n * KP1;
        const float v = (k < 78) ? w1[k * HID + n] : 0.0f;
        const __hip_bfloat16 h = __float2bfloat16(v);
        w1Th[idx] = __builtin_bit_cast(ushort, h);
        w1Tl[idx] = bfb(v - __bfloat162float(h));
    } else if (idx < CONV_ELEMS) {
        const int i = idx - 128 * KP1;
        const int n = i >> 7, k = i & 127;
        const float v = w2[k * HID + n];
        const __hip_bfloat16 h = __float2bfloat16(v);
        w2Th[i] = __builtin_bit_cast(ushort, h);
        w2Tl[i] = bfb(v - __bfloat162float(h));
    }
}

// ---- fused kernel: ballot-ladder 20-NN select + features + MFMA MLP + maxpool.
// One 21.76 KB LDS buffer hosts (in time order): survivor list -> fS -> h1S.
// launch_bounds(256,5): unified VGPR+AGPR cap ~102; two-pass n-tile MFMA loops
// keep peak ~90 (round-13's (256,7) cap 73 caused 43 MB/dispatch scratch spills).
__global__ __launch_bounds__(256, 5) void fused_kernel(
    const float* __restrict__ pos, const float* __restrict__ ori,
    const float* __restrict__ b1, const float* __restrict__ b2,
    const float* __restrict__ w3, const float* __restrict__ b3,
    const ushort* __restrict__ w1Th, const ushort* __restrict__ w1Tl,
    const ushort* __restrict__ w2Th, const ushort* __restrict__ w2Tl,
    float* __restrict__ out)
{
    __shared__ __align__(16) char uS[MROWS * H1P * 2];   // 21760 B union buffer
    __hip_bfloat16 (*const fS)[FP] = (__hip_bfloat16 (*)[FP])uS;
    ushort (*const h1S)[H1P] = (ushort (*)[H1P])uS;
    unsigned long long* const survS = (unsigned long long*)uS;  // [PPB][SURVCAP]

    __shared__ ushort cntS[4][PPB][NTHR];
    __shared__ ushort nbrS[PPB][K];
    __shared__ float  RpS[PPB][9];
    __shared__ float  red[4][PPB];
    __shared__ float  thrS[PPB];
    __shared__ uint   scntS[PPB];

    const int pid0 = blockIdx.x * PPB;
    const int b  = pid0 >> 10;
    const int nb = pid0 & (N - 1);
    const int t  = threadIdx.x;
    const float* posb = pos + (size_t)b * N * 3;
    const float* orib = ori + (size_t)b * N * 9;

    if (t < PPB) scntS[t] = 0;
    if (t < PPB * 9) RpS[t / 9][t % 9] = orib[(size_t)(nb + t / 9) * 9 + (t % 9)];

    float cx[PPB], cy[PPB], cz[PPB];
#pragma unroll
    for (int p = 0; p < PPB; ++p) {
        cx[p] = posb[(nb + p) * 3 + 0];
        cy[p] = posb[(nb + p) * 3 + 1];
        cz[p] = posb[(nb + p) * 3 + 2];
    }

    // ---- select phase 1: r2 for 4 particles x 4 candidates (in registers) ----
    float r2v[PPB][4];
#pragma unroll
    for (int q = 0; q < 4; ++q) {
        const int j = t + q * 256;
        const float px = posb[j * 3 + 0];
        const float py = posb[j * 3 + 1];
        const float pz = posb[j * 3 + 2];
#pragma unroll
        for (int p = 0; p < PPB; ++p) {
            const float dx = pbc(__fsub_rn(cx[p], px));
            const float dy = pbc(__fsub_rn(cy[p], py));
            const float dz = pbc(__fsub_rn(cz[p], pz));
            float r2 = __fadd_rn(__fadd_rn(__fmul_rn(dx, dx), __fmul_rn(dy, dy)),
                                 __fmul_rn(dz, dz));
            if (j == nb + p) r2 = 1e9f;     // self-exclude: never below any THR
            r2v[p][q] = r2;
        }
    }

    // ---- select phase 2: per-wave ballot counts per (particle, threshold) ----
    {
        const int wv = t >> 6, lane = t & 63;
#pragma unroll
        for (int p = 0; p < PPB; ++p) {
#pragma unroll
            for (int i = 0; i < NTHR; ++i) {
                uint c = 0;
#pragma unroll
                for (int q = 0; q < 4; ++q)
                    c += (uint)__popcll(__ballot(r2v[p][q] < THRC[i]));
                if (lane == 0) cntS[wv][p][i] = (ushort)c;
            }
        }
    }
    __syncthreads();

    {   // wave p: pick first threshold with total count >= K
        const int p = t >> 6, lane = t & 63;
        uint tot = 0;
        float thrv = 0.0f;
        if (lane < NTHR) {
            tot = (uint)cntS[0][p][lane] + cntS[1][p][lane]
                + (uint)cntS[2][p][lane] + cntS[3][p][lane];
#pragma unroll
            for (int i = 0; i < NTHR; ++i) if (lane == i) thrv = THRC[i];
        }
        const unsigned long long m = __ballot(lane < NTHR && tot >= (uint)K);
        const int sel = __ffsll((long long)m) - 1;
        if (lane == sel) thrS[p] = thrv;
    }
    __syncthreads();

    // compact survivors into survS (aliases uS; fS not yet written)
#pragma unroll
    for (int p = 0; p < PPB; ++p) {
        const float thr = thrS[p];
#pragma unroll
        for (int q = 0; q < 4; ++q) {
            if (r2v[p][q] < thr) {
                const uint pp = atomicAdd(&scntS[p], 1u);
                if (pp < (uint)SURVCAP)
                    survS[p * SURVCAP + pp] =
                        ((unsigned long long)__float_as_uint(r2v[p][q]) << 32)
                        | (uint)(t + q * 256);
            }
        }
    }
    __syncthreads();

    {   // exact rank by counting; order == lax.top_k (r2 asc, idx asc)
        const int p = t >> 6;
        const int S = min((int)scntS[p], SURVCAP);
        const unsigned long long* sp = survS + p * SURVCAP;
#pragma unroll
        for (int half = 0; half < 2; ++half) {
            const int s = (t & 63) + half * 64;
            if (s < S) {
                const unsigned long long me = sp[s];
                int rank = 0;
                for (int jj = 0; jj < S; ++jj) rank += (sp[jj] < me) ? 1 : 0;
                if (rank < K) nbrS[p][rank] = (ushort)(me & 0xffffULL);
            }
        }
    }
    __syncthreads();            // survS reads done -> uS free for fS

    // ---- features: 80 lanes (p = t/20, k = t%20) -> fS[p*20+k] ----
    if (t < PPB * K) {
        const int p = t / K, k = t - p * K;
        const int j = (int)nbrS[p][k];
        float Rp[9], Rn[9];
#pragma unroll
        for (int q = 0; q < 9; ++q) Rp[q] = RpS[p][q];
#pragma unroll
        for (int q = 0; q < 9; ++q) Rn[q] = orib[(size_t)j * 9 + q];

        const float dx = pbc(__fsub_rn(cx[p], posb[j * 3 + 0]));
        const float dy = pbc(__fsub_rn(cy[p], posb[j * 3 + 1]));
        const float dz = pbc(__fsub_rn(cz[p], posb[j * 3 + 2]));
        const float r2 = __fadd_rn(__fadd_rn(__fmul_rn(dx, dx), __fmul_rn(dy, dy)),
                                   __fmul_rn(dz, dz));
        const float r = sqrtf(r2);
        const float invr = 1.0f / r;
        const float ux = dx * invr, uy = dy * invr, uz = dz * invr;

        __hip_bfloat16* f = fS[p * K + k];
        f[0] = __float2bfloat16(r);
        f[1] = __float2bfloat16(invr);
        f[2] = __float2bfloat16(ux);
        f[3] = __float2bfloat16(uy);
        f[4] = __float2bfloat16(uz);

        float diag[3];
#pragma unroll
        for (int i = 0; i < 3; ++i) {
#pragma unroll
            for (int l = 0; l < 3; ++l) {
                float s = 0.0f, en2 = 0.0f;
#pragma unroll
                for (int m = 0; m < 3; ++m) {
                    const float e = Rp[i * 3 + m] * Rn[l * 3 + m];
                    f[14 + i * 9 + l * 3 + m] = __float2bfloat16(e);
                    en2 += e * e;
                    s += e;
                }
                f[5 + i * 3 + l] = __float2bfloat16(s);
                f[41 + i * 3 + l] = __float2bfloat16(sqrtf(en2));
                float rr = 0.0f;
#pragma unroll
                for (int m = 0; m < 3; ++m) rr += Rp[m * 3 + i] * Rn[m * 3 + l];
                f[62 + i * 3 + l] = __float2bfloat16(rr);
                if (i == l) diag[i] = rr;
            }
        }
#pragma unroll
        for (int i = 0; i < 3; ++i) {
            const float ax = Rp[i * 3 + 0], ay = Rp[i * 3 + 1], az = Rp[i * 3 + 2];
            const float bx = Rn[i * 3 + 0], by = Rn[i * 3 + 1], bz = Rn[i * 3 + 2];
            const float ccx = ay * bz - az * by;
            const float ccy = az * bx - ax * bz;
            const float ccz = ax * by - ay * bx;
            f[50 + i * 3 + 0] = __float2bfloat16(ccx);
            f[50 + i * 3 + 1] = __float2bfloat16(ccy);
            f[50 + i * 3 + 2] = __float2bfloat16(ccz);
            f[59 + i] = __float2bfloat16(sqrtf(ccx * ccx + ccy * ccy + ccz * ccz));
            const float dp = ux * ax + uy * ay + uz * az;
            f[71 + i] = __float2bfloat16(__expf(-dp * dp));
            const float dn = ux * bx + uy * by + uz * bz;
            f[74 + i] = __float2bfloat16(__expf(-dn * dn));
        }
        const float tr = diag[0] + diag[1] + diag[2];
        float ca = (tr - 1.0f) * 0.5f;
        ca = fminf(fmaxf(ca, -1.0f + 1e-6f), 1.0f - 1e-6f);
        f[77] = __float2bfloat16(acosf(ca));
#pragma unroll
        for (int i = 78; i < KP1; ++i) f[i] = __float2bfloat16(0.0f);
    }
    __syncthreads();

    // ---- MFMA MLP: wave wv owns cols [32wv,32wv+32); M = 80 (5 m-tiles) ----
    // Two-pass n-tile loops: only one n-tile's (bh,bl) live at a time (8 VGPR),
    // keeping unified reg peak under the (256,5) cap.
    const int wv = t >> 6, ln = t & 63;
    const int lr = ln & 15, lg = ln >> 4;
    const int n0 = wv * 32 + lr, n1 = n0 + 16;

    f32x4 acc[MT][2];
#pragma unroll
    for (int nt = 0; nt < 2; ++nt) {
        const int nn = (nt == 0) ? n0 : n1;
        const float bb = b1[nn];
#pragma unroll
        for (int mt = 0; mt < MT; ++mt) acc[mt][nt] = f32x4{bb, bb, bb, bb};
        const ushort* pbh = w1Th + nn * KP1 + lg * 8;
        const ushort* pbl = w1Tl + nn * KP1 + lg * 8;
#pragma unroll
        for (int ks = 0; ks < 3; ++ks) {
            const short8 bh = *reinterpret_cast<const short8*>(pbh + ks * 32);
            const short8 bl = *reinterpret_cast<const short8*>(pbl + ks * 32);
#pragma unroll
            for (int mt = 0; mt < MT; ++mt) {
                const short8 a = *reinterpret_cast<const short8*>(
                    &fS[16 * mt + lr][ks * 32 + lg * 8]);
                acc[mt][nt] = __builtin_amdgcn_mfma_f32_16x16x32_bf16(a, bh, acc[mt][nt], 0, 0, 0);
                acc[mt][nt] = __builtin_amdgcn_mfma_f32_16x16x32_bf16(a, bl, acc[mt][nt], 0, 0, 0);
            }
        }
    }
    __syncthreads();    // union aliasing: ALL fS reads complete before h1 writes
#pragma unroll
    for (int mt = 0; mt < MT; ++mt)
#pragma unroll
        for (int r = 0; r < 4; ++r) {
            h1S[16 * mt + 4 * lg + r][n0] = bfb(tanh_f(acc[mt][0][r]));
            h1S[16 * mt + 4 * lg + r][n1] = bfb(tanh_f(acc[mt][1][r]));
        }
    __syncthreads();

    // layer 2: K = 128, two-pass n-tiles
#pragma unroll
    for (int nt = 0; nt < 2; ++nt) {
        const int nn = (nt == 0) ? n0 : n1;
        const float bb = b2[nn];
#pragma unroll
        for (int mt = 0; mt < MT; ++mt) acc[mt][nt] = f32x4{bb, bb, bb, bb};
        const ushort* pbh = w2Th + nn * HID + lg * 8;
        const ushort* pbl = w2Tl + nn * HID + lg * 8;
#pragma unroll
        for (int ks = 0; ks < 4; ++ks) {
            const short8 bh = *reinterpret_cast<const short8*>(pbh + ks * 32);
            const short8 bl = *reinterpret_cast<const short8*>(pbl + ks * 32);
#pragma unroll
            for (int mt = 0; mt < MT; ++mt) {
                const short8 a = *reinterpret_cast<const short8*>(
                    &h1S[16 * mt + lr][ks * 32 + lg * 8]);
                acc[mt][nt] = __builtin_amdgcn_mfma_f32_16x16x32_bf16(a, bh, acc[mt][nt], 0, 0, 0);
                acc[mt][nt] = __builtin_amdgcn_mfma_f32_16x16x32_bf16(a, bl, acc[mt][nt], 0, 0, 0);
            }
        }
    }

    // ---- epilogue: tanh, masked per-particle maxpool, dot w3 ----
#pragma unroll
    for (int mt = 0; mt < MT; ++mt)
#pragma unroll
        for (int nt = 0; nt < 2; ++nt)
#pragma unroll
            for (int r = 0; r < 4; ++r) acc[mt][nt][r] = tanh_f(acc[mt][nt][r]);

    const float w3n0 = w3[n0], w3n1 = w3[n1];
#pragma unroll
    for (int p = 0; p < PPB; ++p) {
        float m0 = -3.0e38f, m1 = -3.0e38f;
#pragma unroll
        for (int mt = 0; mt < MT; ++mt) {
            const bool in = (uint)(4 * mt + lg - 5 * p) < 5u;
#pragma unroll
            for (int r = 0; r < 4; ++r) {
                m0 = fmaxf(m0, in ? acc[mt][0][r] : -3.0e38f);
                m1 = fmaxf(m1, in ? acc[mt][1][r] : -3.0e38f);
            }
        }
        m0 = fmaxf(m0, __shfl_xor(m0, 16, 64));
        m0 = fmaxf(m0, __shfl_xor(m0, 32, 64));
        m1 = fmaxf(m1, __shfl_xor(m1, 16, 64));
        m1 = fmaxf(m1, __shfl_xor(m1, 32, 64));
        float v = m0 * w3n0 + m1 * w3n1;
#pragma unroll
        for (int off = 1; off < 16; off <<= 1) v += __shfl_xor(v, off, 64);
        if (ln == 0) red[wv][p] = v;
    }
    __syncthreads();
    if (t < PPB) out[pid0 + t] = red[0][t] + red[1][t] + red[2][t] + red[3][t] + b3[0];
}

} // namespace

extern "C" void kernel_launch(void* const* d_in, const int* in_sizes, int n_in,
                              void* d_out, int out_size, void* d_ws, size_t ws_size,
                              hipStream_t stream) {
    const float* pos = (const float*)d_in[0];
    const float* ori = (const float*)d_in[1];
    const float* w1  = (const float*)d_in[2];
    const float* b1  = (const float*)d_in[3];
    const float* w2  = (const float*)d_in[4];
    const float* b2  = (const float*)d_in[5];
    const float* w3  = (const float*)d_in[6];
    const float* b3  = (const float*)d_in[7];
    float* out = (float*)d_out;

    // ws: w1T hi/lo (12288 ea) + w2T hi/lo (16384 ea) = 57344 ushorts = 114688 B
    ushort* w1Th = (ushort*)d_ws;
    ushort* w1Tl = w1Th + 128 * KP1;
    ushort* w2Th = w1Tl + 128 * KP1;
    ushort* w2Tl = w2Th + 128 * 128;

    conv_w_kernel<<<dim3(GRID_CONV), dim3(256), 0, stream>>>(
        w1, w2, w1Th, w1Tl, w2Th, w2Tl);
    fused_kernel<<<dim3(GRID_SEL), dim3(256), 0, stream>>>(
        pos, ori, b1, b2, w3, b3, w1Th, w1Tl, w2Th, w2Tl, out);
}